// Round 8
// baseline (504.716 us; speedup 1.0000x reference)
//
#include <hip/hip_runtime.h>

// ---------------------------------------------------------------------------
// CrossScaleSelectiveScan: resize+concat+proj_in -> dual GRU scans -> gate+proj_out
// B=8, C=128, H=W=64.  All GEMMs via v_mfma_f32_16x16x32_bf16.
// R4: ABLATION ROUND. k_scan_t<V>: V0=real, V1=noGX-loads, V2=noSTORE,
//     V3=noSYNC(no barrier/LDS exchange). V1-V3 run on 32 blocks into scratch.
//     k_projin: xb/xbT writes staged through LDS, coalesced dumps.
// (R7 = identical resubmit; R4/R5/R6 benches failed on infra.)
// ---------------------------------------------------------------------------

typedef __bf16 bf16;
typedef _Float16 f16;
typedef __attribute__((ext_vector_type(8))) __bf16 bf16x8;
typedef __attribute__((ext_vector_type(4))) __bf16 bf16x4;
typedef __attribute__((ext_vector_type(4))) _Float16 f16x4;
typedef __attribute__((ext_vector_type(4))) float f32x4;
typedef __attribute__((ext_vector_type(2))) float f32x2;
typedef __attribute__((ext_vector_type(2))) int i32x2;

__device__ __forceinline__ f32x4 mfma16(bf16x8 a, bf16x8 b, f32x4 c) {
  return __builtin_amdgcn_mfma_f32_16x16x32_bf16(a, b, c, 0, 0, 0);
}
__device__ __forceinline__ float sigm(float x) { return 1.0f / (1.0f + __expf(-x)); }
__device__ __forceinline__ float tanh_fast(float x) {
  float e = __expf(2.0f * x);
  return 1.0f - 2.0f / (e + 1.0f);
}

// ---------------------------------------------------------------------------
// K0: weights -> bf16 in ws.
// ---------------------------------------------------------------------------
__global__ __launch_bounds__(256) void k_prep(
    const float* __restrict__ wpi, const float* __restrict__ wihh,
    const float* __restrict__ whhh, const float* __restrict__ wihw,
    const float* __restrict__ whhw, const float* __restrict__ wg,
    const float* __restrict__ wpo, bf16* __restrict__ dst) {
  int i = blockIdx.x * 256 + threadIdx.x;
  if (i < 49152) dst[i] = (bf16)wpi[i];
  else if (i < 98304) dst[i] = (bf16)wihh[i - 49152];
  else if (i < 147456) dst[i] = (bf16)whhh[i - 98304];
  else if (i < 196608) dst[i] = (bf16)wihw[i - 147456];
  else if (i < 245760) dst[i] = (bf16)whhw[i - 196608];
  else if (i < 262144) dst[i] = (bf16)wg[i - 245760];
  else if (i < 278528) dst[i] = (bf16)wpo[i - 262144];
}

// ---------------------------------------------------------------------------
// K1: per (b,h) row: resize+concat [64w][384c] in LDS, proj_in GEMM, BN+ReLU.
// xb/xbT staged via LDS (union with xin) then dumped coalesced.
// ---------------------------------------------------------------------------
__global__ __launch_bounds__(512, 2) void k_projin(
    const float* __restrict__ lp, const float* __restrict__ mp,
    const float* __restrict__ sp, const float* __restrict__ pscale,
    const float* __restrict__ pshift, const bf16* __restrict__ Wpi,
    f16* __restrict__ xf16, bf16* __restrict__ xb, bf16* __restrict__ xbT) {
  __shared__ __align__(16) bf16 xin[64][392];
  const int tid = threadIdx.x;
  const int bb = blockIdx.x >> 6;
  const int h = blockIdx.x & 63;

  {  // ---- phase A: resize + concat into LDS ----
    const int wq = tid & 63, cq = tid >> 6;
    float wy[4]; int iy[4];
    {
      float ssum = 0.f;
#pragma unroll
      for (int dy = 0; dy < 4; ++dy) {
        int y = 2 * h - 1 + dy;
        bool ok = (y >= 0) && (y < 128);
        iy[dy] = ok ? y : 0;
        float w0 = (dy == 0 || dy == 3) ? 0.125f : 0.375f;
        wy[dy] = ok ? w0 : 0.f;
        ssum += wy[dy];
      }
      float inv = 1.f / ssum;
#pragma unroll
      for (int dy = 0; dy < 4; ++dy) wy[dy] *= inv;
    }
    float wx[4];
    {
      float ssum = 0.f;
#pragma unroll
      for (int dx = 0; dx < 4; ++dx) {
        int xq = 2 * wq - 1 + dx;
        bool ok = (xq >= 0) && (xq < 128);
        float w0 = (dx == 0 || dx == 3) ? 0.125f : 0.375f;
        wx[dx] = ok ? w0 : 0.f;
        ssum += wx[dx];
      }
      float inv = 1.f / ssum;
#pragma unroll
      for (int dx = 0; dx < 4; ++dx) wx[dx] *= inv;
    }
    int syA, syB; float wsyA, wsyB;
    {
      int j0 = (h - 1) >> 1;
      float f = (h & 1) ? 0.25f : 0.75f;
      float a = 1.f - f, b2 = f;
      if (j0 < 0) a = 0.f;
      if (j0 + 1 > 31) b2 = 0.f;
      float inv = 1.f / (a + b2);
      wsyA = a * inv; wsyB = b2 * inv;
      syA = j0 < 0 ? 0 : j0;
      syB = (j0 + 1 > 31) ? 31 : (j0 + 1);
    }
    int sxA, sxB; float wsxA, wsxB;
    {
      int j0 = (wq - 1) >> 1;
      float f = (wq & 1) ? 0.25f : 0.75f;
      float a = 1.f - f, b2 = f;
      if (j0 < 0) a = 0.f;
      if (j0 + 1 > 31) b2 = 0.f;
      float inv = 1.f / (a + b2);
      wsxA = a * inv; wsxB = b2 * inv;
      sxA = j0 < 0 ? 0 : j0;
      sxB = (j0 + 1 > 31) ? 31 : (j0 + 1);
    }
#pragma unroll 4
    for (int ci = 0; ci < 16; ++ci) {
      int c = cq * 16 + ci;
      const float* lc = lp + ((size_t)(bb * 128 + c) << 14);
      float acc = 0.f;
#pragma unroll
      for (int dy = 0; dy < 4; ++dy) {
        const float* row = lc + (iy[dy] << 7);
        f32x2 v = *(const f32x2*)&row[2 * wq];
        float bprev = __shfl_up(v.y, 1);
        float anext = __shfl_down(v.x, 1);
        float rs = wx[0] * bprev + wx[1] * v.x + wx[2] * v.y + wx[3] * anext;
        acc = fmaf(wy[dy], rs, acc);
      }
      xin[wq][c] = (bf16)acc;
      xin[wq][128 + c] = (bf16)mp[((bb * 128 + c) * 64 + h) * 64 + wq];
      const float* sc = sp + ((size_t)(bb * 128 + c) << 10);
      float sv = wsyA * (wsxA * sc[(syA << 5) + sxA] + wsxB * sc[(syA << 5) + sxB]) +
                 wsyB * (wsxA * sc[(syB << 5) + sxA] + wsxB * sc[(syB << 5) + sxB]);
      xin[wq][256 + c] = (bf16)sv;
    }
  }
  __syncthreads();

  // ---- phase B: MFMA proj_in (M=128 out-ch over 8 waves, N=64 w, K=384) ----
  const int lane = tid & 63, wv = tid >> 6;
  const int l16 = lane & 15, k8 = (lane >> 4) * 8, j4 = (lane >> 4) * 4;
  const f32x4 zf = {0.f, 0.f, 0.f, 0.f};
  f32x4 acc[4];
#pragma unroll
  for (int pt = 0; pt < 4; ++pt) acc[pt] = zf;

  for (int kk = 0; kk < 12; ++kk) {
    bf16x8 bfr[4];
#pragma unroll
    for (int pt = 0; pt < 4; ++pt)
      bfr[pt] = *(const bf16x8*)&xin[pt * 16 + l16][kk * 32 + k8];
    bf16x8 afr = *(const bf16x8*)(Wpi + (size_t)(wv * 16 + l16) * 384 + kk * 32 + k8);
#pragma unroll
    for (int pt = 0; pt < 4; ++pt) acc[pt] = mfma16(afr, bfr[pt], acc[pt]);
  }
  __syncthreads();  // all xin reads done; safe to overwrite as xout
  bf16(*xout)[132] = (bf16(*)[132]) & xin[0][0];
  {
    int c0 = wv * 16 + j4;
    f32x4 scv = *(const f32x4*)&pscale[c0];
    f32x4 shv = *(const f32x4*)&pshift[c0];
#pragma unroll
    for (int pt = 0; pt < 4; ++pt) {
      int pw = pt * 16 + l16;
      bf16x4 pk;
#pragma unroll
      for (int j = 0; j < 4; ++j) {
        float v = fmaxf(acc[pt][j] * scv[j] + shv[j], 0.f);
        xf16[(size_t)((bb * 128 + c0 + j) * 64 + h) * 64 + pw] = (f16)v;
        pk[j] = (bf16)v;
      }
      *(bf16x4*)&xout[pw][c0] = pk;
    }
  }
  __syncthreads();
  // coalesced dumps: xb contiguous 16KB; xbT 256B rows at 16KB stride
  bf16* dstb = xb + (size_t)(bb * 4096 + h * 64) * 128;
#pragma unroll
  for (int rep = 0; rep < 2; ++rep) {
    int idx = tid + rep * 512;
    int row = idx >> 4, col8 = (idx & 15) * 8;
    bf16x8 v = *(const bf16x8*)&xout[row][col8];
    *(bf16x8*)&dstb[row * 128 + col8] = v;
    *(bf16x8*)&xbT[(size_t)(bb * 4096 + row * 64 + h) * 128 + col8] = v;
  }
}

// ---------------------------------------------------------------------------
// K2: gx = x*wih^T + bih (+bhh for r,z) in scan-fragment layout:
//   gx[t][nb][part 0..2][tid 0..511][4] f16, part = r|z|n.
// ---------------------------------------------------------------------------
__global__ __launch_bounds__(512, 2) void k_gx(
    const bf16* __restrict__ xb, const bf16* __restrict__ xbT,
    const bf16* __restrict__ wih_h_b, const bf16* __restrict__ wih_w_b,
    const float* __restrict__ bih_h, const float* __restrict__ bih_w,
    const float* __restrict__ bhh_h, const float* __restrict__ bhh_w,
    f16* __restrict__ gxh, f16* __restrict__ gxw) {
  const int dir = blockIdx.z;
  const int nb = blockIdx.y;
  const int t0 = blockIdx.x * 2;
  const bf16* xsrc = dir ? xbT : xb;
  const bf16* wih = dir ? wih_w_b : wih_h_b;
  const float* bih = dir ? bih_w : bih_h;
  const float* bhh = dir ? bhh_w : bhh_h;
  f16* gx = dir ? gxw : gxh;

  const int tid = threadIdx.x, lane = tid & 63, w = tid >> 6;
  const int l16 = lane & 15, k8 = (lane >> 4) * 8, j4 = (lane >> 4) * 4;
  const int n = nb * 16 + l16;
  const int pb = n >> 6, q = n & 63;

  bf16x8 afr[3][4];
#pragma unroll
  for (int part = 0; part < 3; ++part) {
    int gbase = part * 128 + w * 16;
#pragma unroll
    for (int kk = 0; kk < 4; ++kk)
      afr[part][kk] = *(const bf16x8*)(wih + (size_t)(gbase + l16) * 128 + kk * 32 + k8);
  }
  const f32x4 zf = {0.f, 0.f, 0.f, 0.f};
  f32x4 acc[3][2];
#pragma unroll
  for (int part = 0; part < 3; ++part) { acc[part][0] = zf; acc[part][1] = zf; }

#pragma unroll
  for (int pt = 0; pt < 2; ++pt) {
    const bf16* xr = xsrc + (size_t)(pb * 4096 + (t0 + pt) * 64 + q) * 128;
#pragma unroll
    for (int kk = 0; kk < 4; ++kk) {
      bf16x8 bfr = *(const bf16x8*)(xr + kk * 32 + k8);
#pragma unroll
      for (int part = 0; part < 3; ++part)
        acc[part][pt] = mfma16(afr[part][kk], bfr, acc[part][pt]);
    }
  }
#pragma unroll
  for (int part = 0; part < 3; ++part) {
    int g0 = part * 128 + w * 16 + j4;
    f32x4 bi = *(const f32x4*)&bih[g0];
    if (part < 2) {
      f32x4 bh = *(const f32x4*)&bhh[g0];
#pragma unroll
      for (int j = 0; j < 4; ++j) bi[j] += bh[j];
    }
#pragma unroll
    for (int pt = 0; pt < 2; ++pt) {
      f16x4 pk;
#pragma unroll
      for (int j = 0; j < 4; ++j) pk[j] = (f16)(acc[part][pt][j] + bi[j]);
      *(f16x4*)&gx[((size_t)(((t0 + pt) * 32 + nb) * 3 + part) * 512 + tid) * 4] = pk;
    }
  }
}

// ---------------------------------------------------------------------------
// K3: GRU scans, templated ablation.
// V0: real (R3 structure).  V1: no gx loads.  V2: no per-step stores.
// V3: no barrier + no LDS h-exchange (loop-carried reg B-operand).
// ---------------------------------------------------------------------------
template <int V>
__global__ __launch_bounds__(512, 2) void k_scan_t(
    const bf16* __restrict__ whh_h_b, const bf16* __restrict__ whh_w_b,
    const float* __restrict__ bhh_h, const float* __restrict__ bhh_w,
    const f16* __restrict__ gxh, const f16* __restrict__ gxw,
    f16* __restrict__ ohb, f16* __restrict__ owb) {
  const int dir = blockIdx.x >> 5;
  const int nb = blockIdx.x & 31;
  const bf16* whh = dir ? whh_w_b : whh_h_b;
  const float* bhh = dir ? bhh_w : bhh_h;
  const f16* gx = dir ? gxw : gxh;
  f16* outb = dir ? owb : ohb;

  __shared__ __align__(16) bf16 hbuf[2][16][136];

  const int tid = threadIdx.x, lane = tid & 63, w = tid >> 6;
  const int l16 = lane & 15, k8 = (lane >> 4) * 8, j4 = (lane >> 4) * 4;
  const int cc0 = w * 16 + j4;

  bf16x8 afr[3][4];
#pragma unroll
  for (int part = 0; part < 3; ++part) {
    int gbase = part * 128 + w * 16;
#pragma unroll
    for (int kk = 0; kk < 4; ++kk)
      afr[part][kk] = *(const bf16x8*)(whh + (size_t)(gbase + l16) * 128 + kk * 32 + k8);
  }
  const f32x4 bhn = *(const f32x4*)&bhh[256 + cc0];

  for (int i = tid; i < 2 * 16 * 136; i += 512) ((bf16*)hbuf)[i] = (bf16)0.f;

  const int n = nb * 16 + l16;
  const int pb = n >> 6, q = n & 63;
  const int pbase0 = pb * 4096 + (dir ? q * 64 : q);
  const int pstep = dir ? 1 : 64;

  f16x4 gq[4][3];
#pragma unroll
  for (int tp = 0; tp < 2; ++tp) {
    const size_t b0 = ((size_t)(tp * 32 + nb) * 3) * 512 + tid;
    gq[tp][0] = *(const f16x4*)&gx[b0 * 4];
    gq[tp][1] = *(const f16x4*)&gx[(b0 + 512) * 4];
    gq[tp][2] = *(const f16x4*)&gx[(b0 + 1024) * 4];
  }
  f32x4 hreg = {0.f, 0.f, 0.f, 0.f};

  __builtin_amdgcn_sched_barrier(0);
  asm volatile("s_waitcnt lgkmcnt(0)");
  __builtin_amdgcn_s_barrier();
  __builtin_amdgcn_sched_barrier(0);

  const f32x4 zf = {0.f, 0.f, 0.f, 0.f};
  for (int tb = 0; tb < 16; ++tb) {
#pragma unroll
    for (int u = 0; u < 4; ++u) {
      const int t = tb * 4 + u;
      if constexpr (V != 1) {  // prefetch t+2
        int tp = t + 2 < 64 ? t + 2 : 63;
        const size_t b0 = ((size_t)(tp * 32 + nb) * 3) * 512 + tid;
        gq[(u + 2) & 3][0] = *(const f16x4*)&gx[b0 * 4];
        gq[(u + 2) & 3][1] = *(const f16x4*)&gx[(b0 + 512) * 4];
        gq[(u + 2) & 3][2] = *(const f16x4*)&gx[(b0 + 1024) * 4];
      } else {  // loop-carried register substitute (no loads)
        f16x4 fake;
#pragma unroll
        for (int j = 0; j < 4; ++j) fake[j] = (f16)hreg[j];
        gq[(u + 2) & 3][0] = fake;
        gq[(u + 2) & 3][1] = fake;
        gq[(u + 2) & 3][2] = fake;
      }
      const int cur = u & 1;
      bf16x8 hb[4];
      if constexpr (V != 3) {
#pragma unroll
        for (int kk = 0; kk < 4; ++kk)
          hb[kk] = *(const bf16x8*)&hbuf[cur][l16][kk * 32 + k8];
      } else {  // loop-carried register B-operand (no LDS, no barrier)
        bf16x4 p;
#pragma unroll
        for (int j = 0; j < 4; ++j) p[j] = (bf16)hreg[j];
        bf16x8 d;
#pragma unroll
        for (int j = 0; j < 4; ++j) { d[j] = p[j]; d[4 + j] = p[j]; }
#pragma unroll
        for (int kk = 0; kk < 4; ++kk) hb[kk] = d;
      }
      f32x4 aR = zf, aZ = zf, aN = zf;
#pragma unroll
      for (int kk = 0; kk < 4; ++kk) {
        aR = mfma16(afr[0][kk], hb[kk], aR);
        aZ = mfma16(afr[1][kk], hb[kk], aZ);
        aN = mfma16(afr[2][kk], hb[kk], aN);
      }
      bf16x4 hb4;
      f16x4 o4;
#pragma unroll
      for (int j = 0; j < 4; ++j) {
        float r = sigm((float)gq[u][0][j] + aR[j]);
        float z = sigm((float)gq[u][1][j] + aZ[j]);
        float nn = tanh_fast((float)gq[u][2][j] + r * (aN[j] + bhn[j]));
        float h = nn + z * (hreg[j] - nn);
        hreg[j] = h;
        hb4[j] = (bf16)h;
        o4[j] = (f16)h;
      }
      if constexpr (V != 3) *(bf16x4*)&hbuf[cur ^ 1][l16][cc0] = hb4;
      if constexpr (V != 2) {
        *(f16x4*)&outb[(size_t)(pbase0 + t * pstep) * 128 + cc0] = o4;
      } else {  // keep o4 live without the store
        i32x2 sink = *(i32x2*)&o4;
        asm volatile("" ::"v"(sink.x), "v"(sink.y));
      }
      if constexpr (V != 3) {
        __builtin_amdgcn_sched_barrier(0);
        asm volatile("s_waitcnt lgkmcnt(0)");
        __builtin_amdgcn_s_barrier();
        __builtin_amdgcn_sched_barrier(0);
      }
    }
  }
  if constexpr (V == 2) {  // single final store keeps the chain observable
    *(f16x4*)&outb[(size_t)(pbase0 + 63 * pstep) * 128 + cc0] =
        f16x4{(f16)hreg[0], (f16)hreg[1], (f16)hreg[2], (f16)hreg[3]};
  }
}

// ---------------------------------------------------------------------------
// K4: scanned = oh+ow; gate = sigmoid(scanned@gate_w^T+b); gated = scanned*gate;
// out = relu(gated@proj_out^T * scale + shift) + x.  One (b,h) row per block.
// ---------------------------------------------------------------------------
__global__ __launch_bounds__(256, 2) void k_final(
    const f16* __restrict__ ohb, const f16* __restrict__ owb,
    const bf16* __restrict__ Wg, const float* __restrict__ gate_b,
    const bf16* __restrict__ Wpo, const float* __restrict__ poscale,
    const float* __restrict__ poshift, const f16* __restrict__ xf16,
    float* __restrict__ out) {
  __shared__ __align__(16) float sf[64][132];
  __shared__ __align__(16) bf16 sb[64][136];
  __shared__ __align__(16) bf16 gbuf[64][136];
  const int tid = threadIdx.x;
  const int bb = blockIdx.x >> 6, h = blockIdx.x & 63;
  const int pbase = bb * 4096 + h * 64;
  for (int i = tid; i < 2048; i += 256) {
    int w = i >> 5, cg = (i & 31) * 4;
    size_t idx = (size_t)(pbase + w) * 128 + cg;
    f16x4 a = *(const f16x4*)&ohb[idx];
    f16x4 b = *(const f16x4*)&owb[idx];
    f32x4 v;
    bf16x4 pk;
#pragma unroll
    for (int j = 0; j < 4; ++j) {
      v[j] = (float)a[j] + (float)b[j];
      pk[j] = (bf16)v[j];
    }
    *(f32x4*)&sf[w][cg] = v;
    *(bf16x4*)&sb[w][cg] = pk;
  }
  __syncthreads();
  const int lane = tid & 63, wv = tid >> 6;
  const int l16 = lane & 15, k8 = (lane >> 4) * 8, j4 = (lane >> 4) * 4;
  const f32x4 zf = {0.f, 0.f, 0.f, 0.f};
  f32x4 acc[2][4];
#pragma unroll
  for (int i = 0; i < 2; ++i)
#pragma unroll
    for (int pt = 0; pt < 4; ++pt) acc[i][pt] = zf;
#pragma unroll
  for (int kk = 0; kk < 4; ++kk) {
    bf16x8 bfr[4];
#pragma unroll
    for (int pt = 0; pt < 4; ++pt)
      bfr[pt] = *(const bf16x8*)&sb[pt * 16 + l16][kk * 32 + k8];
#pragma unroll
    for (int i = 0; i < 2; ++i) {
      bf16x8 afr = *(const bf16x8*)(Wg + (size_t)((wv * 2 + i) * 16 + l16) * 128 + kk * 32 + k8);
#pragma unroll
      for (int pt = 0; pt < 4; ++pt) acc[i][pt] = mfma16(afr, bfr[pt], acc[i][pt]);
    }
  }
#pragma unroll
  for (int i = 0; i < 2; ++i) {
    int o0 = (wv * 2 + i) * 16 + j4;
    f32x4 gb4 = *(const f32x4*)&gate_b[o0];
#pragma unroll
    for (int pt = 0; pt < 4; ++pt) {
      int pc = pt * 16 + l16;
      f32x4 sv = *(const f32x4*)&sf[pc][o0];
      bf16x4 pk;
#pragma unroll
      for (int j = 0; j < 4; ++j) {
        float g = sigm(acc[i][pt][j] + gb4[j]);
        pk[j] = (bf16)(sv[j] * g);
      }
      *(bf16x4*)&gbuf[pc][o0] = pk;
    }
  }
  __syncthreads();
  f32x4 acc2[2][4];
#pragma unroll
  for (int i = 0; i < 2; ++i)
#pragma unroll
    for (int pt = 0; pt < 4; ++pt) acc2[i][pt] = zf;
#pragma unroll
  for (int kk = 0; kk < 4; ++kk) {
    bf16x8 bfr[4];
#pragma unroll
    for (int pt = 0; pt < 4; ++pt)
      bfr[pt] = *(const bf16x8*)&gbuf[pt * 16 + l16][kk * 32 + k8];
#pragma unroll
    for (int i = 0; i < 2; ++i) {
      bf16x8 afr = *(const bf16x8*)(Wpo + (size_t)((wv * 2 + i) * 16 + l16) * 128 + kk * 32 + k8);
#pragma unroll
      for (int pt = 0; pt < 4; ++pt) acc2[i][pt] = mfma16(afr, bfr[pt], acc2[i][pt]);
    }
  }
#pragma unroll
  for (int i = 0; i < 2; ++i) {
    int o0 = (wv * 2 + i) * 16 + j4;
    f32x4 scv = *(const f32x4*)&poscale[o0];
    f32x4 shv = *(const f32x4*)&poshift[o0];
#pragma unroll
    for (int pt = 0; pt < 4; ++pt) {
      int pc = pt * 16 + l16;
#pragma unroll
      for (int j = 0; j < 4; ++j) {
        int oc = o0 + j;
        size_t oi = (size_t)((bb * 128 + oc) * 64 + h) * 64 + pc;
        float v = fmaxf(acc2[i][pt][j] * scv[j] + shv[j], 0.f) + (float)xf16[oi];
        out[oi] = v;
      }
    }
  }
}

// ---------------------------------------------------------------------------
// ws layout (bytes), total 92,831,744:
//   [0,        557056)     weights bf16
//   [557056,   8945664)    x f16  [b][c][h][w]   (residual)
//   [8945664,  17334272)   xb bf16 [b,h,w][c]    (+ ablation oh-scratch)
//   [17334272, 25722880)   xbT bf16 [b,w,h][c]   (+ ablation ow-scratch)
//   [25722880, 50888704)   gx_h f16 [t][nb][3][512][4]
//   [50888704, 76054528)   gx_w f16
//   [76054528, 84443136)   oh f16 [p][c]
//   [84443136, 92831744)   ow f16
// ---------------------------------------------------------------------------
extern "C" void kernel_launch(void* const* d_in, const int* in_sizes, int n_in,
                              void* d_out, int out_size, void* d_ws, size_t ws_size,
                              hipStream_t stream) {
  const float* lp = (const float*)d_in[0];
  const float* mp = (const float*)d_in[1];
  const float* sp = (const float*)d_in[2];
  const float* proj_in_w = (const float*)d_in[3];
  const float* proj_in_scale = (const float*)d_in[4];
  const float* proj_in_shift = (const float*)d_in[5];
  const float* wih_h = (const float*)d_in[6];
  const float* whh_h = (const float*)d_in[7];
  const float* bih_h = (const float*)d_in[8];
  const float* bhh_h = (const float*)d_in[9];
  const float* wih_w = (const float*)d_in[10];
  const float* whh_w = (const float*)d_in[11];
  const float* bih_w = (const float*)d_in[12];
  const float* bhh_w = (const float*)d_in[13];
  const float* gate_w = (const float*)d_in[14];
  const float* gate_b = (const float*)d_in[15];
  const float* proj_out_w = (const float*)d_in[16];
  const float* proj_out_scale = (const float*)d_in[17];
  const float* proj_out_shift = (const float*)d_in[18];
  float* out = (float*)d_out;

  char* ws = (char*)d_ws;
  bf16* wb = (bf16*)ws;
  bf16* Wpi_b = wb + 0;
  bf16* Wih_h_b = wb + 49152;
  bf16* Whh_h_b = wb + 98304;
  bf16* Wih_w_b = wb + 147456;
  bf16* Whh_w_b = wb + 196608;
  bf16* Wg_b = wb + 245760;
  bf16* Wpo_b = wb + 262144;
  f16* xf16 = (f16*)(ws + 557056);
  bf16* xb = (bf16*)(ws + 8945664);
  bf16* xbT = (bf16*)(ws + 17334272);
  f16* gxh = (f16*)(ws + 25722880);
  f16* gxw = (f16*)(ws + 50888704);
  f16* ohb = (f16*)(ws + 76054528);
  f16* owb = (f16*)(ws + 84443136);
  f16* oh_s = (f16*)(ws + 8945664);   // scratch for ablations (xb region)
  f16* ow_s = (f16*)(ws + 17334272);  // scratch for ablations (xbT region)

  k_prep<<<dim3(1088), dim3(256), 0, stream>>>(proj_in_w, wih_h, whh_h, wih_w,
                                               whh_w, gate_w, proj_out_w, wb);
  k_projin<<<dim3(512), dim3(512), 0, stream>>>(lp, mp, sp, proj_in_scale,
                                                proj_in_shift, Wpi_b, xf16, xb, xbT);
  k_gx<<<dim3(32, 32, 2), dim3(512), 0, stream>>>(xb, xbT, Wih_h_b, Wih_w_b,
                                                  bih_h, bih_w, bhh_h, bhh_w,
                                                  gxh, gxw);
  // ---- ablation probes (dir 0 only, scratch outputs; xb/xbT dead now) ----
  k_scan_t<1><<<dim3(32), dim3(512), 0, stream>>>(Whh_h_b, Whh_w_b, bhh_h, bhh_w,
                                                  gxh, gxw, oh_s, ow_s);
  k_scan_t<2><<<dim3(32), dim3(512), 0, stream>>>(Whh_h_b, Whh_w_b, bhh_h, bhh_w,
                                                  gxh, gxw, oh_s, ow_s);
  k_scan_t<3><<<dim3(32), dim3(512), 0, stream>>>(Whh_h_b, Whh_w_b, bhh_h, bhh_w,
                                                  gxh, gxw, oh_s, ow_s);
  // ---- real scan ----
  k_scan_t<0><<<dim3(64), dim3(512), 0, stream>>>(Whh_h_b, Whh_w_b, bhh_h, bhh_w,
                                                  gxh, gxw, ohb, owb);
  k_final<<<dim3(512), dim3(256), 0, stream>>>(ohb, owb, Wg_b, gate_b, Wpo_b,
                                               proj_out_scale, proj_out_shift,
                                               xf16, out);
}